// Round 6
// baseline (1495.539 us; speedup 1.0000x reference)
//
#include <hip/hip_runtime.h>
#include <hip/hip_bf16.h>
#include <math.h>

// ---------------- problem constants ----------------
#define B_   32
#define L_   512
#define C_   64
#define D_   512
#define H_   8
#define EL_  3
#define DFF_ 2048
#define NC_  8
#define PH_  256
#define DK_  64
#define NTOK (B_*L_)   // 16384

typedef unsigned short u16;
typedef unsigned int   u32;
typedef __attribute__((ext_vector_type(4))) float f32x4;
typedef __attribute__((ext_vector_type(8))) short s16x8;

__device__ __forceinline__ u16 f2b(float f){           // f32 -> bf16 (RNE)
  u32 u = __float_as_uint(f);
  u32 r = (u + 0x7fffu + ((u >> 16) & 1u)) >> 16;
  return (u16)r;
}
__device__ __forceinline__ float b2f(u16 u){ return __uint_as_float(((u32)u) << 16); }

__device__ __forceinline__ void gload16(const void* g, void* l){
  __builtin_amdgcn_global_load_lds(
      (const __attribute__((address_space(1))) u32*)g,
      (__attribute__((address_space(3))) u32*)l, 16, 0, 0);
}

__device__ __forceinline__ float gelu_exact(float x){
  return 0.5f * x * (1.f + erff(x * 0.70710678118654752f));
}

// ---------------- small prep kernels ----------------

__global__ __launch_bounds__(256) void k_stats(const float* __restrict__ x,
    float* __restrict__ mean, float* __restrict__ stdv){
  int b = blockIdx.x, t = threadIdx.x;
  const float* p = x + (size_t)b*L_*C_;
  float s = 0.f, q = 0.f;
  for (int i = t; i < L_*C_; i += 256){ float v = p[i]; s += v; q += v*v; }
  __shared__ float ss[256], qq[256];
  ss[t] = s; qq[t] = q;
  __syncthreads();
  if (t < 64){
    float S = ss[t]+ss[t+64]+ss[t+128]+ss[t+192];
    float Q = qq[t]+qq[t+64]+qq[t+128]+qq[t+192];
    float m = S*(1.f/L_);
    mean[b*64+t] = m;
    stdv[b*64+t] = sqrtf(Q*(1.f/L_) - m*m + 1e-5f);
  }
}

// tau / delta projector MLPs. blockIdx.x = b, blockIdx.y = 0(tau)/1(delta)
__global__ __launch_bounds__(256) void k_mlp(const float* __restrict__ x,
    const float* __restrict__ mean, const float* __restrict__ stdv,
    const float* __restrict__ cw_t, const float* __restrict__ w1t, const float* __restrict__ b1t,
    const float* __restrict__ w2t, const float* __restrict__ b2t, const float* __restrict__ w3t,
    const float* __restrict__ cw_d, const float* __restrict__ w1d, const float* __restrict__ b1d,
    const float* __restrict__ w2d, const float* __restrict__ b2d, const float* __restrict__ w3d,
    float* __restrict__ tau, float* __restrict__ delta)
{
  int b = blockIdx.x, sel = blockIdx.y, t = threadIdx.x;
  const float* cw = sel ? cw_d : cw_t;
  const float* w1 = sel ? w1d : w1t;  const float* b1 = sel ? b1d : b1t;
  const float* w2 = sel ? w2d : w2t;  const float* b2 = sel ? b2d : b2t;
  const float* st = sel ? mean : stdv;
  __shared__ float h0[128], h1s[256], h2s[256], red[256];
  __shared__ float c4[4][64];
  {
    int c = t & 63, g = t >> 6;
    int cm = (c+63)&63, cp = (c+1)&63;
    const float* xrow = x + (size_t)b*L_*C_;
    float acc = 0.f;
    for (int s = g*128; s < (g+1)*128; ++s){
      const float* r = xrow + s*C_;
      acc += r[cm]*cw[s*3] + r[c]*cw[s*3+1] + r[cp]*cw[s*3+2];
    }
    c4[g][c] = acc;
  }
  __syncthreads();
  if (t < 64)       h0[t] = c4[0][t]+c4[1][t]+c4[2][t]+c4[3][t];
  else if (t < 128) h0[t] = st[b*64 + (t-64)];
  __syncthreads();
  { float a = b1[t]; for (int j=0;j<128;++j) a += h0[j]*w1[t*128+j]; h1s[t] = fmaxf(a,0.f); }
  __syncthreads();
  { float a = b2[t]; for (int j=0;j<256;++j) a += h1s[j]*w2[t*256+j]; h2s[t] = fmaxf(a,0.f); }
  __syncthreads();
  if (sel == 0){
    red[t] = h2s[t]*w3t[t];
    __syncthreads();
    for (int o=128;o>0;o>>=1){ if (t<o) red[t]+=red[t+o]; __syncthreads(); }
    if (t == 0) tau[b] = expf(red[0]);
  } else {
    for (int l = t; l < L_; l += 256){
      float a = 0.f;
      for (int j=0;j<256;++j) a += h2s[j]*w3d[l*256+j];
      delta[b*L_ + l] = a;
    }
  }
}

// sinusoidal positional encoding table (L,D)
__global__ void k_pe(float* __restrict__ pe){
  int i = blockIdx.x*256 + threadIdx.x;
  if (i >= L_*D_/2) return;
  int l = i >> 8, j = i & 255;
  float div = expf((float)(2*j) * (-9.210340371976184f / (float)D_));
  float arg = (float)l * div;
  pe[l*D_ + 2*j]   = sinf(arg);
  pe[l*D_ + 2*j+1] = cosf(arg);
}

// im2col: awin[(b,l), k*64+c] = x_enc[b,(l+k-1)%L,c], bf16
__global__ void k_awin(const float* __restrict__ x, u16* __restrict__ awin){
  int i = blockIdx.x*256 + threadIdx.x;
  if (i >= NTOK*192) return;
  int col = i % 192, row = i / 192;
  int k = col >> 6, c = col & 63;
  int b = row >> 9, l = row & 511;
  int ls = (l + k + 511) & 511;
  awin[i] = f2b(x[((size_t)((b<<9) | ls))*64 + c]);
}

// emb_conv_w (D,C,3) -> embB[d, k*64+c] bf16
__global__ void k_embw(const float* __restrict__ w, u16* __restrict__ o){
  int i = blockIdx.x*256 + threadIdx.x;
  if (i >= D_*192) return;
  int d = i / 192, col = i % 192, k = col >> 6, c = col & 63;
  o[i] = f2b(w[(d*64 + c)*3 + k]);
}

// concat Wq|Wk|Wv -> (EL,1536,512) bf16
__global__ void k_packqkv(const float* __restrict__ Wq, const float* __restrict__ Wk,
                          const float* __restrict__ Wv, u16* __restrict__ o){
  int i = blockIdx.x*256 + threadIdx.x;
  if (i >= EL_*1536*D_) return;
  int e = i / (1536*D_), r = i % (1536*D_);
  int n = r / D_, k = r % D_;
  const float* src = (n < 512) ? Wq + ((size_t)e*512 + n)*512 + k
                   : (n < 1024) ? Wk + ((size_t)e*512 + (n-512))*512 + k
                                : Wv + ((size_t)e*512 + (n-1024))*512 + k;
  o[i] = f2b(*src);
}
__global__ void k_packb(const float* __restrict__ bq, const float* __restrict__ bk,
                        const float* __restrict__ bv, float* __restrict__ o){
  int i = blockIdx.x*256 + threadIdx.x;
  if (i >= EL_*1536) return;
  int e = i/1536, n = i%1536;
  o[i] = (n<512) ? bq[e*512+n] : (n<1024) ? bk[e*512+n-512] : bv[e*512+n-1024];
}

__global__ void k_f2b(const float* __restrict__ in, u16* __restrict__ out, int n){
  int i = blockIdx.x*256 + threadIdx.x;
  if (i < n) out[i] = f2b(in[i]);
}

// ---------------- 128x128 MFMA GEMM (embed / O-proj / FFN2) ----------------
// T2 swizzle: source-permuted staging + XOR'd reads (chunk = 16B, cb ^= row&7).
__global__ __launch_bounds__(256,2) void k_gemm(
    const u16* __restrict__ A, const u16* __restrict__ Bm,
    int M, int N, int K,
    const float* __restrict__ bias, const float* __restrict__ pe,
    int dogelu,
    float* __restrict__ outF, u16* __restrict__ outB)
{
  __shared__ u16 As[128*64];
  __shared__ u16 Bs[128*64];
  int tid = threadIdx.x;
  int l = tid & 63, w = tid >> 6;
  int wr = w >> 1, wc = w & 1;
  int lo = l & 15, lg = l >> 4;

  int flat = blockIdx.x + gridDim.x*blockIdx.y;
  int nwg  = gridDim.x*gridDim.y;
  int n1   = ((nwg & 7) == 0) ? ((flat & 7)*(nwg >> 3) + (flat >> 3)) : flat;
  int bx   = n1 % gridDim.x, by = n1 / gridDim.x;
  int m0 = by * 128, n0 = bx * 128;

  f32x4 acc[4][4];
  #pragma unroll
  for (int m=0;m<4;++m)
    #pragma unroll
    for (int n=0;n<4;++n) acc[m][n] = (f32x4){0.f,0.f,0.f,0.f};

  int swz = lo & 7;
  int ktn = K >> 6;
  for (int kt = 0; kt < ktn; ++kt){
    #pragma unroll
    for (int i=0;i<4;++i){
      int cA = i*256 + tid;
      int row = cA >> 3, sub = (cA & 7) ^ (row & 7);
      gload16(A  + (size_t)(m0+row)*K + kt*64 + sub*8, &As[cA*8]);
      gload16(Bm + (size_t)(n0+row)*K + kt*64 + sub*8, &Bs[cA*8]);
    }
    __syncthreads();
    #pragma unroll
    for (int kk=0;kk<2;++kk){
      int cb = ((kk<<2)|lg) ^ swz;
      s16x8 af[4], bfr[4];
      #pragma unroll
      for (int m=0;m<4;++m) af[m]  = *(const s16x8*)&As[(wr*64 + m*16 + lo)*64 + cb*8];
      #pragma unroll
      for (int n=0;n<4;++n) bfr[n] = *(const s16x8*)&Bs[(wc*64 + n*16 + lo)*64 + cb*8];
      #pragma unroll
      for (int m=0;m<4;++m)
        #pragma unroll
        for (int n=0;n<4;++n)
          acc[m][n] = __builtin_amdgcn_mfma_f32_16x16x32_bf16(af[m], bfr[n], acc[m][n], 0,0,0);
    }
    __syncthreads();
  }

  #pragma unroll
  for (int m=0;m<4;++m){
    int rbase = m0 + wr*64 + m*16 + lg*4;
    #pragma unroll
    for (int n=0;n<4;++n){
      int col = n0 + wc*64 + n*16 + lo;
      float bv = bias ? bias[col] : 0.f;
      #pragma unroll
      for (int r=0;r<4;++r){
        int row = rbase + r;
        float v = acc[m][n][r] + bv;
        if (pe) v += pe[(size_t)(row & 511)*N + col];
        if (dogelu) v = gelu_exact(v);
        size_t o = (size_t)row*N + col;
        if (outF) outF[o] = v;
        if (outB) outB[o] = f2b(v);
      }
    }
  }
}

// ---------------- 256x256 deep-pipelined MFMA GEMM (QKV / FFN1) ----------------
// 8 waves (2x4), BK=64, 128KB dbuf LDS. Per K-tile: front-load next tile's 8
// global_load_lds (T14 issue-early), then 4 quadrant phases
// {12 swizzled ds_read_b128 -> setprio(1) -> 16 MFMA -> setprio(0) -> sched_barrier}.
// One __syncthreads per K-tile (vmcnt drain lands ~4 phases after issue = amortized).
__global__ __launch_bounds__(512,2) void k_gemm256(
    const u16* __restrict__ A, const u16* __restrict__ Bm,
    int M, int N, int K,
    const float* __restrict__ bias,
    int dogelu,
    float* __restrict__ outF, u16* __restrict__ outB)
{
  __shared__ u16 AS[2][256*64];
  __shared__ u16 BS[2][256*64];
  int tid = threadIdx.x;
  int l = tid & 63, w = tid >> 6;
  int wr = w >> 2, wc = w & 3;          // 2 x 4 waves
  int lo = l & 15, lg = l >> 4;
  int swz = lo & 7;

  int flat = blockIdx.x + gridDim.x*blockIdx.y;
  int nwg  = gridDim.x*gridDim.y;
  int n1   = ((nwg & 7) == 0) ? ((flat & 7)*(nwg >> 3) + (flat >> 3)) : flat;
  int bx   = n1 % gridDim.x, by = n1 / gridDim.x;
  int m0 = by * 256, n0 = bx * 256;

  f32x4 acc[8][4];
  #pragma unroll
  for (int m=0;m<8;++m)
    #pragma unroll
    for (int n=0;n<4;++n) acc[m][n] = (f32x4){0.f,0.f,0.f,0.f};

  // stage one K-tile (A: 256x64, B: 256x64), source-permuted for read swizzle
  auto STAGE = [&](int buf, int kt){
    #pragma unroll
    for (int i=0;i<4;++i){
      int c = i*512 + tid;                      // 0..2047 chunks of 16B
      int row = c >> 3, sub = (c & 7) ^ (row & 7);
      gload16(A  + (size_t)(m0+row)*K + kt*64 + sub*8, &AS[buf][c*8]);
      gload16(Bm + (size_t)(n0+row)*K + kt*64 + sub*8, &BS[buf][c*8]);
    }
  };

  STAGE(0, 0);
  __syncthreads();

  int ktn = K >> 6;
  for (int kt = 0; kt < ktn; ++kt){
    int cur = kt & 1;
    if (kt + 1 < ktn) STAGE(cur^1, kt+1);      // issue-early; drains at tile end
    const u16* Ac = &AS[cur][0];
    const u16* Bc = &BS[cur][0];

    #pragma unroll
    for (int q=0;q<4;++q){
      int qm = q >> 1, qn = q & 1;
      s16x8 af[4][2], bf2[2][2];
      #pragma unroll
      for (int mm=0;mm<4;++mm)
        #pragma unroll
        for (int ks=0;ks<2;++ks){
          int row = wr*128 + (qm*4+mm)*16 + lo;
          int cb  = ((ks<<2)|lg) ^ swz;
          af[mm][ks] = *(const s16x8*)&Ac[row*64 + cb*8];
        }
      #pragma unroll
      for (int nn=0;nn<2;++nn)
        #pragma unroll
        for (int ks=0;ks<2;++ks){
          int row = wc*64 + (qn*2+nn)*16 + lo;
          int cb  = ((ks<<2)|lg) ^ swz;
          bf2[nn][ks] = *(const s16x8*)&Bc[row*64 + cb*8];
        }
      __builtin_amdgcn_s_setprio(1);
      #pragma unroll
      for (int mm=0;mm<4;++mm)
        #pragma unroll
        for (int nn=0;nn<2;++nn)
          #pragma unroll
          for (int ks=0;ks<2;++ks)
            acc[qm*4+mm][qn*2+nn] = __builtin_amdgcn_mfma_f32_16x16x32_bf16(
                af[mm][ks], bf2[nn][ks], acc[qm*4+mm][qn*2+nn], 0,0,0);
      __builtin_amdgcn_s_setprio(0);
      __builtin_amdgcn_sched_barrier(0);
    }
    __syncthreads();   // all waves done with cur; own next-tile loads drained
  }

  #pragma unroll
  for (int m=0;m<8;++m){
    int rbase = m0 + wr*128 + m*16 + lg*4;
    #pragma unroll
    for (int n=0;n<4;++n){
      int col = n0 + wc*64 + n*16 + lo;
      float bv = bias ? bias[col] : 0.f;
      #pragma unroll
      for (int r=0;r<4;++r){
        int row = rbase + r;
        float v = acc[m][n][r] + bv;
        if (dogelu) v = gelu_exact(v);
        size_t o = (size_t)row*N + col;
        if (outF) outF[o] = v;
        if (outB) outB[o] = f2b(v);
      }
    }
  }
}

// ---------------- V transpose: qkv v-slice -> vT (B,H,DK,L) bf16 ----------------
__global__ __launch_bounds__(256) void k_vt(const u16* __restrict__ qkv, u16* __restrict__ vT){
  int st = blockIdx.x, h = blockIdx.y, b = blockIdx.z;
  __shared__ u16 tile[64][72];
  int t = threadIdx.x;
  int r = t >> 2, q = t & 3;
  const u16* src = qkv + ((size_t)(b*L_ + st*64 + r))*1536 + 1024 + h*64 + q*16;
  #pragma unroll
  for (int j=0;j<16;++j) tile[r][q*16+j] = src[j];
  __syncthreads();
  u16* dst = vT + (((size_t)(b*H_ + h))*64 + r)*L_ + st*64 + q*16;
  #pragma unroll
  for (int j=0;j<16;++j) dst[j] = tile[q*16+j][r];
}

// ---------------- flash attention, LDS-staged K/V, double-buffered ----------------
__global__ __launch_bounds__(256) void k_attn(
    const u16* __restrict__ qkv, const u16* __restrict__ vT,
    const float* __restrict__ tau, const float* __restrict__ delta,
    u16* __restrict__ obf)
{
  __shared__ u16 Ks[2][64*64];
  __shared__ u16 Vs[2][64*64];
  __shared__ u16 plds[4][16*64];
  int id = blockIdx.x;
  int qt = id >> 8, hb = id & 255, h = hb >> 5, b = hb & 31;
  int tid = threadIdx.x, l = tid & 63, w = tid >> 6;
  int lo = l & 15, lg = l >> 4;
  int q0 = qt*64 + w*16;

  const u16* qrow = qkv + ((size_t)(b*L_ + q0 + lo))*1536 + h*64;
  s16x8 qf0 = *(const s16x8*)(qrow + lg*8);
  s16x8 qf1 = *(const s16x8*)(qrow + 32 + lg*8);

  const u16* Kg = qkv + (size_t)b*L_*1536 + 512 + h*64;
  const u16* Vg = vT + ((size_t)(b*H_ + h))*64*L_;

  float taus = tau[b] * 0.125f;
  f32x4 oacc[4];
  #pragma unroll
  for (int n=0;n<4;++n) oacc[n] = (f32x4){0.f,0.f,0.f,0.f};
  float mrow[4] = {-3e38f,-3e38f,-3e38f,-3e38f};
  float lrow[4] = {0.f,0.f,0.f,0.f};
  const float* dptr = delta + b*L_;
  u16* pw = &plds[w][0];

  auto STAGE = [&](int buf, int s0){
    #pragma unroll
    for (int i=0;i<2;++i){
      int c = i*256 + tid;
      int row = c >> 3, sub = (c & 7) ^ (row & 7);
      gload16(Kg + (size_t)(s0 + row)*1536 + sub*8, &Ks[buf][c*8]);
      gload16(Vg + (size_t)row*L_ + s0 + sub*8,     &Vs[buf][c*8]);
    }
  };

  STAGE(0, 0);
  __syncthreads();

  int swz = lo & 7;
  for (int it = 0; it < 8; ++it){
    int s0 = it*64, cur = it & 1;
    if (it < 7) STAGE(cur^1, s0 + 64);
    const u16* Kc = &Ks[cur][0];
    const u16* Vc = &Vs[cur][0];

    f32x4 sacc[4];
    #pragma unroll
    for (int t2=0;t2<4;++t2) sacc[t2] = (f32x4){0.f,0.f,0.f,0.f};
    #pragma unroll
    for (int kk=0;kk<2;++kk){
      #pragma unroll
      for (int t2=0;t2<4;++t2){
        s16x8 kf = *(const s16x8*)&Kc[(t2*16 + lo)*64 + (((kk*4 + lg) ^ swz)*8)];
        sacc[t2] = __builtin_amdgcn_mfma_f32_16x16x32_bf16(kk ? qf1 : qf0, kf, sacc[t2], 0,0,0);
      }
    }

    float p[4][4];
    float rm[4] = {-3e38f,-3e38f,-3e38f,-3e38f};
    #pragma unroll
    for (int t2=0;t2<4;++t2){
      float dl = dptr[s0 + t2*16 + lo] * 0.125f;
      #pragma unroll
      for (int r=0;r<4;++r){
        float sc = taus*sacc[t2][r] + dl;
        p[t2][r] = sc;
        rm[r] = fmaxf(rm[r], sc);
      }
    }
    #pragma unroll
    for (int r=0;r<4;++r){
      #pragma unroll
      for (int off=1; off<16; off<<=1) rm[r] = fmaxf(rm[r], __shfl_xor(rm[r], off));
    }
    float alpha[4];
    #pragma unroll
    for (int r=0;r<4;++r){
      float mn = fmaxf(mrow[r], rm[r]);
      alpha[r] = __expf(mrow[r] - mn);
      mrow[r] = mn;
      float acc = 0.f;
      #pragma unroll
      for (int t2=0;t2<4;++t2){ p[t2][r] = __expf(p[t2][r] - mn); acc += p[t2][r]; }
      #pragma unroll
      for (int off=1; off<16; off<<=1) acc += __shfl_xor(acc, off);
      lrow[r] = lrow[r]*alpha[r] + acc;
    }
    #pragma unroll
    for (int n=0;n<4;++n)
      #pragma unroll
      for (int r=0;r<4;++r) oacc[n][r] *= alpha[r];

    #pragma unroll
    for (int t2=0;t2<4;++t2)
      #pragma unroll
      for (int r=0;r<4;++r){
        int q = lg*4 + r;
        int cb = (t2*2 + (lo>>3)) ^ (q & 7);
        pw[q*64 + cb*8 + (lo & 7)] = f2b(p[t2][r]);
      }
    asm volatile("" ::: "memory");
    #pragma unroll
    for (int kk=0;kk<2;++kk){
      s16x8 pa = *(const s16x8*)&pw[lo*64 + (((kk*4 + lg) ^ swz)*8)];
      #pragma unroll
      for (int n=0;n<4;++n){
        s16x8 vf = *(const s16x8*)&Vc[(n*16 + lo)*64 + (((kk*4 + lg) ^ swz)*8)];
        oacc[n] = __builtin_amdgcn_mfma_f32_16x16x32_bf16(pa, vf, oacc[n], 0,0,0);
      }
    }
    __syncthreads();
  }

  float inv[4];
  #pragma unroll
  for (int r=0;r<4;++r) inv[r] = 1.f / lrow[r];
  #pragma unroll
  for (int n=0;n<4;++n)
    #pragma unroll
    for (int r=0;r<4;++r){
      int row = q0 + lg*4 + r;
      int col = h*64 + n*16 + lo;
      obf[((size_t)(b*L_ + row))*512 + col] = f2b(oacc[n][r]*inv[r]);
    }
}

// ---------------- LayerNorm (optional residual add, optional gelu) ----------------
__global__ __launch_bounds__(256) void k_ln(const float* __restrict__ X, const float* __restrict__ R,
    const float* __restrict__ gw, const float* __restrict__ bw,
    float* __restrict__ outF, u16* __restrict__ outB, int dogelu)
{
  int l = threadIdx.x & 63, w = threadIdx.x >> 6;
  size_t row = (size_t)blockIdx.x*4 + w;
  const float4* x4 = (const float4*)(X + row*D_);
  float4 a0 = x4[l*2], a1 = x4[l*2+1];
  if (R){
    const float4* r4 = (const float4*)(R + row*D_);
    float4 c0 = r4[l*2], c1 = r4[l*2+1];
    a0.x+=c0.x; a0.y+=c0.y; a0.z+=c0.z; a0.w+=c0.w;
    a1.x+=c1.x; a1.y+=c1.y; a1.z+=c1.z; a1.w+=c1.w;
  }
  float v[8] = {a0.x,a0.y,a0.z,a0.w,a1.x,a1.y,a1.z,a1.w};
  float s = 0.f, q = 0.f;
  #pragma unroll
  for (int j=0;j<8;++j){ s += v[j]; q += v[j]*v[j]; }
  #pragma unroll
  for (int off=1; off<64; off<<=1){ s += __shfl_xor(s, off); q += __shfl_xor(q, off); }
  float mean = s * (1.f/D_);
  float var  = q * (1.f/D_) - mean*mean;
  float rstd = rsqrtf(var + 1e-5f);
  int c0i = l*8;
  #pragma unroll
  for (int j=0;j<8;++j){
    int c = c0i + j;
    float t = (v[j] - mean)*rstd*gw[c] + bw[c];
    if (dogelu) t = gelu_exact(t);
    if (outF) outF[row*D_ + c] = t;
    if (outB) outB[row*D_ + c] = f2b(t);
  }
}

// ---------------- final projection, split-K two-stage ----------------
__global__ __launch_bounds__(256) void k_proj1(const float* __restrict__ g, const float* __restrict__ pw,
    float* __restrict__ pp)
{
  int b = blockIdx.x, nc = blockIdx.y, kc = blockIdx.z, t = threadIdx.x;
  const float4* g4 = (const float4*)(g  + (size_t)b*(L_*D_) + (size_t)kc*32768);
  const float4* w4 = (const float4*)(pw + (size_t)nc*(L_*D_) + (size_t)kc*32768);
  float acc = 0.f;
  for (int k = t; k < 8192; k += 256){
    float4 a = g4[k], c = w4[k];
    acc += a.x*c.x + a.y*c.y + a.z*c.z + a.w*c.w;
  }
  #pragma unroll
  for (int off=1; off<64; off<<=1) acc += __shfl_xor(acc, off);
  __shared__ float red[4];
  if ((t & 63) == 0) red[t>>6] = acc;
  __syncthreads();
  if (t == 0) pp[((b*NC_ + nc)<<3) + kc] = red[0]+red[1]+red[2]+red[3];
}
__global__ void k_proj2(const float* __restrict__ pp, const float* __restrict__ pb,
                        float* __restrict__ out){
  int t = threadIdx.x;
  float s = 0.f;
  #pragma unroll
  for (int k=0;k<8;++k) s += pp[t*8 + k];
  out[t] = s + pb[t & 7];
}

// ---------------- launcher ----------------
extern "C" void kernel_launch(void* const* d_in, const int* in_sizes, int n_in,
                              void* d_out, int out_size, void* d_ws, size_t ws_size,
                              hipStream_t stream)
{
  const float* x_enc        = (const float*)d_in[0];
  const float* emb_conv_w   = (const float*)d_in[1];
  const float* tau_conv_w   = (const float*)d_in[2];
  const float* tau_w1       = (const float*)d_in[3];
  const float* tau_b1       = (const float*)d_in[4];
  const float* tau_w2       = (const float*)d_in[5];
  const float* tau_b2       = (const float*)d_in[6];
  const float* tau_w3       = (const float*)d_in[7];
  const float* delta_conv_w = (const float*)d_in[8];
  const float* delta_w1     = (const float*)d_in[9];
  const float* delta_b1     = (const float*)d_in[10];
  const float* delta_w2     = (const float*)d_in[11];
  const float* delta_b2     = (const float*)d_in[12];
  const float* delta_w3     = (const float*)d_in[13];
  const float* Wq  = (const float*)d_in[14];
  const float* bq  = (const float*)d_in[15];
  const float* Wk  = (const float*)d_in[16];
  const float* bk  = (const float*)d_in[17];
  const float* Wv  = (const float*)d_in[18];
  const float* bv  = (const float*)d_in[19];
  const float* Wo  = (const float*)d_in[20];
  const float* bo  = (const float*)d_in[21];
  const float* ff_w1 = (const float*)d_in[22];
  const float* ff_b1 = (const float*)d_in[23];
  const float* ff_w2 = (const float*)d_in[24];
  const float* ff_b2 = (const float*)d_in[25];
  const float* ln1_g = (const float*)d_in[26];
  const float* ln1_b = (const float*)d_in[27];
  const float* ln2_g = (const float*)d_in[28];
  const float* ln2_b = (const float*)d_in[29];
  const float* norm_g = (const float*)d_in[30];
  const float* norm_b = (const float*)d_in[31];
  const float* proj_w = (const float*)d_in[32];
  const float* proj_b = (const float*)d_in[33];
  (void)in_sizes; (void)n_in; (void)out_size; (void)ws_size;

  char* ws = (char*)d_ws;
  size_t off = 0;
  auto alloc = [&](size_t n){ size_t o = off; off += (n + 255) & ~(size_t)255; return o; };
  float* xf    = (float*)(ws + alloc((size_t)NTOK*512*4));
  u16*   xb    = (u16*)  (ws + alloc((size_t)NTOK*512*2));
  char*  U     =          ws + alloc((size_t)NTOK*2048*2);   // union: qkv | h1 | awin (+obf tail)
  u16*   qkv   = (u16*)U;
  u16*   h1    = (u16*)U;
  u16*   awin  = (u16*)U;
  u16*   obf   = (u16*)(U + (size_t)NTOK*1536*2);
  u16*   vT    = (u16*)  (ws + alloc((size_t)NTOK*512*2));
  float* tmp   = (float*)(ws + alloc((size_t)NTOK*512*4));
  float* pe    = (float*)(ws + alloc((size_t)512*512*4));
  u16*   WqkvB = (u16*)  (ws + alloc((size_t)EL_*1536*512*2));
  u16*   WoB   = (u16*)  (ws + alloc((size_t)EL_*512*512*2));
  u16*   W1B   = (u16*)  (ws + alloc((size_t)EL_*2048*512*2));
  u16*   W2B   = (u16*)  (ws + alloc((size_t)EL_*512*2048*2));
  u16*   embB  = (u16*)  (ws + alloc((size_t)512*192*2));
  float* bqkv  = (float*)(ws + alloc((size_t)EL_*1536*4));
  float* meanb = (float*)(ws + alloc(2048*4));
  float* stdb  = (float*)(ws + alloc(2048*4));
  float* taub  = (float*)(ws + alloc(256));
  float* deltab= (float*)(ws + alloc((size_t)B_*512*4));
  float* pp    = (float*)(ws + alloc((size_t)B_*NC_*8*4));

  k_packqkv<<<(EL_*1536*512+255)/256, 256, 0, stream>>>(Wq, Wk, Wv, WqkvB);
  k_packb  <<<(EL_*1536+255)/256,     256, 0, stream>>>(bq, bk, bv, bqkv);
  k_f2b    <<<(EL_*512*512+255)/256,  256, 0, stream>>>(Wo, WoB, EL_*512*512);
  k_f2b    <<<(EL_*2048*512+255)/256, 256, 0, stream>>>(ff_w1, W1B, EL_*2048*512);
  k_f2b    <<<(EL_*512*2048+255)/256, 256, 0, stream>>>(ff_w2, W2B, EL_*512*2048);
  k_embw   <<<(D_*192+255)/256,       256, 0, stream>>>(emb_conv_w, embB);

  k_stats<<<B_, 256, 0, stream>>>(x_enc, meanb, stdb);
  k_mlp<<<dim3(B_,2), 256, 0, stream>>>(x_enc, meanb, stdb,
      tau_conv_w, tau_w1, tau_b1, tau_w2, tau_b2, tau_w3,
      delta_conv_w, delta_w1, delta_b1, delta_w2, delta_b2, delta_w3,
      taub, deltab);
  k_pe  <<<(L_*D_/2+255)/256, 256, 0, stream>>>(pe);
  k_awin<<<(NTOK*192+255)/256, 256, 0, stream>>>(x_enc, awin);

  k_gemm<<<dim3(4,128), 256, 0, stream>>>(awin, embB, NTOK, 512, 192, nullptr, pe, 0, xf, xb);

  for (int e = 0; e < EL_; ++e){
    k_gemm256<<<dim3(6,64), 512, 0, stream>>>(xb, WqkvB + (size_t)e*1536*512, NTOK, 1536, 512,
                                              bqkv + e*1536, 0, nullptr, qkv);
    k_vt  <<<dim3(8,8,32), 256, 0, stream>>>(qkv, vT);
    k_attn<<<2048, 256, 0, stream>>>(qkv, vT, taub, deltab, obf);
    k_gemm<<<dim3(4,128), 256, 0, stream>>>(obf, WoB + (size_t)e*512*512, NTOK, 512, 512,
                                            bo + e*512, nullptr, 0, tmp, nullptr);
    k_ln  <<<NTOK/4, 256, 0, stream>>>(xf, tmp, ln1_g + e*512, ln1_b + e*512, xf, xb, 0);
    k_gemm256<<<dim3(8,64), 512, 0, stream>>>(xb, W1B + (size_t)e*2048*512, NTOK, 2048, 512,
                                              ff_b1 + e*2048, 1, nullptr, h1);
    k_gemm<<<dim3(4,128), 256, 0, stream>>>(h1, W2B + (size_t)e*512*2048, NTOK, 512, 2048,
                                            ff_b2 + e*512, nullptr, 0, tmp, nullptr);
    k_ln  <<<NTOK/4, 256, 0, stream>>>(xf, tmp, ln2_g + e*512, ln2_b + e*512, xf,
                                       (e == EL_-1) ? nullptr : xb, 0);
  }

  k_ln   <<<NTOK/4, 256, 0, stream>>>(xf, nullptr, norm_g, norm_b, tmp, nullptr, 1);
  k_proj1<<<dim3(B_,NC_,8), 256, 0, stream>>>(tmp, proj_w, pp);
  k_proj2<<<1, 256, 0, stream>>>(pp, proj_b, (float*)d_out);
}

// Round 7
// 1316.138 us; speedup vs baseline: 1.1363x; 1.1363x over previous
//
#include <hip/hip_runtime.h>
#include <hip/hip_bf16.h>
#include <math.h>

// ---------------- problem constants ----------------
#define B_   32
#define L_   512
#define C_   64
#define D_   512
#define H_   8
#define EL_  3
#define DFF_ 2048
#define NC_  8
#define PH_  256
#define DK_  64
#define NTOK (B_*L_)   // 16384

typedef unsigned short u16;
typedef unsigned int   u32;
typedef __attribute__((ext_vector_type(4))) float f32x4;
typedef __attribute__((ext_vector_type(8))) short s16x8;

__device__ __forceinline__ u16 f2b(float f){           // f32 -> bf16 (RNE)
  u32 u = __float_as_uint(f);
  u32 r = (u + 0x7fffu + ((u >> 16) & 1u)) >> 16;
  return (u16)r;
}
__device__ __forceinline__ float b2f(u16 u){ return __uint_as_float(((u32)u) << 16); }

__device__ __forceinline__ void gload16(const void* g, void* l){
  __builtin_amdgcn_global_load_lds(
      (const __attribute__((address_space(1))) u32*)g,
      (__attribute__((address_space(3))) u32*)l, 16, 0, 0);
}

__device__ __forceinline__ float gelu_exact(float x){
  return 0.5f * x * (1.f + erff(x * 0.70710678118654752f));
}

// ---------------- small prep kernels ----------------

__global__ __launch_bounds__(256) void k_stats(const float* __restrict__ x,
    float* __restrict__ mean, float* __restrict__ stdv){
  int b = blockIdx.x, t = threadIdx.x;
  const float* p = x + (size_t)b*L_*C_;
  float s = 0.f, q = 0.f;
  for (int i = t; i < L_*C_; i += 256){ float v = p[i]; s += v; q += v*v; }
  __shared__ float ss[256], qq[256];
  ss[t] = s; qq[t] = q;
  __syncthreads();
  if (t < 64){
    float S = ss[t]+ss[t+64]+ss[t+128]+ss[t+192];
    float Q = qq[t]+qq[t+64]+qq[t+128]+qq[t+192];
    float m = S*(1.f/L_);
    mean[b*64+t] = m;
    stdv[b*64+t] = sqrtf(Q*(1.f/L_) - m*m + 1e-5f);
  }
}

// tau / delta projector MLPs. blockIdx.x = b, blockIdx.y = 0(tau)/1(delta)
__global__ __launch_bounds__(256) void k_mlp(const float* __restrict__ x,
    const float* __restrict__ mean, const float* __restrict__ stdv,
    const float* __restrict__ cw_t, const float* __restrict__ w1t, const float* __restrict__ b1t,
    const float* __restrict__ w2t, const float* __restrict__ b2t, const float* __restrict__ w3t,
    const float* __restrict__ cw_d, const float* __restrict__ w1d, const float* __restrict__ b1d,
    const float* __restrict__ w2d, const float* __restrict__ b2d, const float* __restrict__ w3d,
    float* __restrict__ tau, float* __restrict__ delta)
{
  int b = blockIdx.x, sel = blockIdx.y, t = threadIdx.x;
  const float* cw = sel ? cw_d : cw_t;
  const float* w1 = sel ? w1d : w1t;  const float* b1 = sel ? b1d : b1t;
  const float* w2 = sel ? w2d : w2t;  const float* b2 = sel ? b2d : b2t;
  const float* st = sel ? mean : stdv;
  __shared__ float h0[128], h1s[256], h2s[256], red[256];
  __shared__ float c4[4][64];
  {
    int c = t & 63, g = t >> 6;
    int cm = (c+63)&63, cp = (c+1)&63;
    const float* xrow = x + (size_t)b*L_*C_;
    float acc = 0.f;
    for (int s = g*128; s < (g+1)*128; ++s){
      const float* r = xrow + s*C_;
      acc += r[cm]*cw[s*3] + r[c]*cw[s*3+1] + r[cp]*cw[s*3+2];
    }
    c4[g][c] = acc;
  }
  __syncthreads();
  if (t < 64)       h0[t] = c4[0][t]+c4[1][t]+c4[2][t]+c4[3][t];
  else if (t < 128) h0[t] = st[b*64 + (t-64)];
  __syncthreads();
  { float a = b1[t]; for (int j=0;j<128;++j) a += h0[j]*w1[t*128+j]; h1s[t] = fmaxf(a,0.f); }
  __syncthreads();
  { float a = b2[t]; for (int j=0;j<256;++j) a += h1s[j]*w2[t*256+j]; h2s[t] = fmaxf(a,0.f); }
  __syncthreads();
  if (sel == 0){
    red[t] = h2s[t]*w3t[t];
    __syncthreads();
    for (int o=128;o>0;o>>=1){ if (t<o) red[t]+=red[t+o]; __syncthreads(); }
    if (t == 0) tau[b] = expf(red[0]);
  } else {
    for (int l = t; l < L_; l += 256){
      float a = 0.f;
      for (int j=0;j<256;++j) a += h2s[j]*w3d[l*256+j];
      delta[b*L_ + l] = a;
    }
  }
}

// sinusoidal positional encoding table (L,D)
__global__ void k_pe(float* __restrict__ pe){
  int i = blockIdx.x*256 + threadIdx.x;
  if (i >= L_*D_/2) return;
  int l = i >> 8, j = i & 255;
  float div = expf((float)(2*j) * (-9.210340371976184f / (float)D_));
  float arg = (float)l * div;
  pe[l*D_ + 2*j]   = sinf(arg);
  pe[l*D_ + 2*j+1] = cosf(arg);
}

// im2col: awin[(b,l), k*64+c] = x_enc[b,(l+k-1)%L,c], bf16
__global__ void k_awin(const float* __restrict__ x, u16* __restrict__ awin){
  int i = blockIdx.x*256 + threadIdx.x;
  if (i >= NTOK*192) return;
  int col = i % 192, row = i / 192;
  int k = col >> 6, c = col & 63;
  int b = row >> 9, l = row & 511;
  int ls = (l + k + 511) & 511;
  awin[i] = f2b(x[((size_t)((b<<9) | ls))*64 + c]);
}

// emb_conv_w (D,C,3) -> embB[d, k*64+c] bf16
__global__ void k_embw(const float* __restrict__ w, u16* __restrict__ o){
  int i = blockIdx.x*256 + threadIdx.x;
  if (i >= D_*192) return;
  int d = i / 192, col = i % 192, k = col >> 6, c = col & 63;
  o[i] = f2b(w[(d*64 + c)*3 + k]);
}

// concat Wq|Wk|Wv -> (EL,1536,512) bf16
__global__ void k_packqkv(const float* __restrict__ Wq, const float* __restrict__ Wk,
                          const float* __restrict__ Wv, u16* __restrict__ o){
  int i = blockIdx.x*256 + threadIdx.x;
  if (i >= EL_*1536*D_) return;
  int e = i / (1536*D_), r = i % (1536*D_);
  int n = r / D_, k = r % D_;
  const float* src = (n < 512) ? Wq + ((size_t)e*512 + n)*512 + k
                   : (n < 1024) ? Wk + ((size_t)e*512 + (n-512))*512 + k
                                : Wv + ((size_t)e*512 + (n-1024))*512 + k;
  o[i] = f2b(*src);
}
__global__ void k_packb(const float* __restrict__ bq, const float* __restrict__ bk,
                        const float* __restrict__ bv, float* __restrict__ o){
  int i = blockIdx.x*256 + threadIdx.x;
  if (i >= EL_*1536) return;
  int e = i/1536, n = i%1536;
  o[i] = (n<512) ? bq[e*512+n] : (n<1024) ? bk[e*512+n-512] : bv[e*512+n-1024];
}

__global__ void k_f2b(const float* __restrict__ in, u16* __restrict__ out, int n){
  int i = blockIdx.x*256 + threadIdx.x;
  if (i < n) out[i] = f2b(in[i]);
}

// ---------------- 128x128 MFMA GEMM (all matmuls) ----------------
// m97-style, T2 swizzle (source-permuted staging + XOR'd reads), XCD chunk swizzle.
// __launch_bounds__(256,4): 4 blocks/CU (32KB LDS x4 = 128 <= 160KB; VGPR 76 <= 128)
// -> inter-block wave overlap fills barrier/vmcnt drains (m114/m97 mechanism).
__global__ __launch_bounds__(256,4) void k_gemm(
    const u16* __restrict__ A, const u16* __restrict__ Bm,
    int M, int N, int K,
    const float* __restrict__ bias, const float* __restrict__ pe,
    int dogelu,
    float* __restrict__ outF, u16* __restrict__ outB)
{
  __shared__ u16 As[128*64];
  __shared__ u16 Bs[128*64];
  int tid = threadIdx.x;
  int l = tid & 63, w = tid >> 6;
  int wr = w >> 1, wc = w & 1;
  int lo = l & 15, lg = l >> 4;

  int flat = blockIdx.x + gridDim.x*blockIdx.y;
  int nwg  = gridDim.x*gridDim.y;
  int n1   = ((nwg & 7) == 0) ? ((flat & 7)*(nwg >> 3) + (flat >> 3)) : flat;
  int bx   = n1 % gridDim.x, by = n1 / gridDim.x;
  int m0 = by * 128, n0 = bx * 128;

  f32x4 acc[4][4];
  #pragma unroll
  for (int m=0;m<4;++m)
    #pragma unroll
    for (int n=0;n<4;++n) acc[m][n] = (f32x4){0.f,0.f,0.f,0.f};

  int swz = lo & 7;
  int ktn = K >> 6;
  for (int kt = 0; kt < ktn; ++kt){
    #pragma unroll
    for (int i=0;i<4;++i){
      int cA = i*256 + tid;
      int row = cA >> 3, sub = (cA & 7) ^ (row & 7);
      gload16(A  + (size_t)(m0+row)*K + kt*64 + sub*8, &As[cA*8]);
      gload16(Bm + (size_t)(n0+row)*K + kt*64 + sub*8, &Bs[cA*8]);
    }
    __syncthreads();
    #pragma unroll
    for (int kk=0;kk<2;++kk){
      int cb = ((kk<<2)|lg) ^ swz;
      s16x8 af[4], bfr[4];
      #pragma unroll
      for (int m=0;m<4;++m) af[m]  = *(const s16x8*)&As[(wr*64 + m*16 + lo)*64 + cb*8];
      #pragma unroll
      for (int n=0;n<4;++n) bfr[n] = *(const s16x8*)&Bs[(wc*64 + n*16 + lo)*64 + cb*8];
      #pragma unroll
      for (int m=0;m<4;++m)
        #pragma unroll
        for (int n=0;n<4;++n)
          acc[m][n] = __builtin_amdgcn_mfma_f32_16x16x32_bf16(af[m], bfr[n], acc[m][n], 0,0,0);
    }
    __syncthreads();
  }

  #pragma unroll
  for (int m=0;m<4;++m){
    int rbase = m0 + wr*64 + m*16 + lg*4;
    #pragma unroll
    for (int n=0;n<4;++n){
      int col = n0 + wc*64 + n*16 + lo;
      float bv = bias ? bias[col] : 0.f;
      #pragma unroll
      for (int r=0;r<4;++r){
        int row = rbase + r;
        float v = acc[m][n][r] + bv;
        if (pe) v += pe[(size_t)(row & 511)*N + col];
        if (dogelu) v = gelu_exact(v);
        size_t o = (size_t)row*N + col;
        if (outF) outF[o] = v;
        if (outB) outB[o] = f2b(v);
      }
    }
  }
}

// ---------------- V transpose: qkv v-slice -> vT (B,H,DK,L) bf16 ----------------
__global__ __launch_bounds__(256) void k_vt(const u16* __restrict__ qkv, u16* __restrict__ vT){
  int st = blockIdx.x, h = blockIdx.y, b = blockIdx.z;
  __shared__ u16 tile[64][72];
  int t = threadIdx.x;
  int r = t >> 2, q = t & 3;
  const u16* src = qkv + ((size_t)(b*L_ + st*64 + r))*1536 + 1024 + h*64 + q*16;
  #pragma unroll
  for (int j=0;j<16;++j) tile[r][q*16+j] = src[j];
  __syncthreads();
  u16* dst = vT + (((size_t)(b*H_ + h))*64 + r)*L_ + st*64 + q*16;
  #pragma unroll
  for (int j=0;j<16;++j) dst[j] = tile[q*16+j][r];
}

// ---------------- flash attention, LDS-staged K/V, double-buffered ----------------
__global__ __launch_bounds__(256,4) void k_attn(
    const u16* __restrict__ qkv, const u16* __restrict__ vT,
    const float* __restrict__ tau, const float* __restrict__ delta,
    u16* __restrict__ obf)
{
  __shared__ u16 Ks[2][64*64];
  __shared__ u16 Vs[2][64*64];
  __shared__ u16 plds[4][16*64];
  int id = blockIdx.x;
  int qt = id >> 8, hb = id & 255, h = hb >> 5, b = hb & 31;
  int tid = threadIdx.x, l = tid & 63, w = tid >> 6;
  int lo = l & 15, lg = l >> 4;
  int q0 = qt*64 + w*16;

  const u16* qrow = qkv + ((size_t)(b*L_ + q0 + lo))*1536 + h*64;
  s16x8 qf0 = *(const s16x8*)(qrow + lg*8);
  s16x8 qf1 = *(const s16x8*)(qrow + 32 + lg*8);

  const u16* Kg = qkv + (size_t)b*L_*1536 + 512 + h*64;
  const u16* Vg = vT + ((size_t)(b*H_ + h))*64*L_;

  float taus = tau[b] * 0.125f;
  f32x4 oacc[4];
  #pragma unroll
  for (int n=0;n<4;++n) oacc[n] = (f32x4){0.f,0.f,0.f,0.f};
  float mrow[4] = {-3e38f,-3e38f,-3e38f,-3e38f};
  float lrow[4] = {0.f,0.f,0.f,0.f};
  const float* dptr = delta + b*L_;
  u16* pw = &plds[w][0];

  auto STAGE = [&](int buf, int s0){
    #pragma unroll
    for (int i=0;i<2;++i){
      int c = i*256 + tid;
      int row = c >> 3, sub = (c & 7) ^ (row & 7);
      gload16(Kg + (size_t)(s0 + row)*1536 + sub*8, &Ks[buf][c*8]);
      gload16(Vg + (size_t)row*L_ + s0 + sub*8,     &Vs[buf][c*8]);
    }
  };

  STAGE(0, 0);
  __syncthreads();

  int swz = lo & 7;
  for (int it = 0; it < 8; ++it){
    int s0 = it*64, cur = it & 1;
    if (it < 7) STAGE(cur^1, s0 + 64);
    const u16* Kc = &Ks[cur][0];
    const u16* Vc = &Vs[cur][0];

    f32x4 sacc[4];
    #pragma unroll
    for (int t2=0;t2<4;++t2) sacc[t2] = (f32x4){0.f,0.f,0.f,0.f};
    #pragma unroll
    for (int kk=0;kk<2;++kk){
      #pragma unroll
      for (int t2=0;t2<4;++t2){
        s16x8 kf = *(const s16x8*)&Kc[(t2*16 + lo)*64 + (((kk*4 + lg) ^ swz)*8)];
        sacc[t2] = __builtin_amdgcn_mfma_f32_16x16x32_bf16(kk ? qf1 : qf0, kf, sacc[t2], 0,0,0);
      }
    }

    float p[4][4];
    float rm[4] = {-3e38f,-3e38f,-3e38f,-3e38f};
    #pragma unroll
    for (int t2=0;t2<4;++t2){
      float dl = dptr[s0 + t2*16 + lo] * 0.125f;
      #pragma unroll
      for (int r=0;r<4;++r){
        float sc = taus*sacc[t2][r] + dl;
        p[t2][r] = sc;
        rm[r] = fmaxf(rm[r], sc);
      }
    }
    #pragma unroll
    for (int r=0;r<4;++r){
      #pragma unroll
      for (int off=1; off<16; off<<=1) rm[r] = fmaxf(rm[r], __shfl_xor(rm[r], off));
    }
    float alpha[4];
    #pragma unroll
    for (int r=0;r<4;++r){
      float mn = fmaxf(mrow[r], rm[r]);
      alpha[r] = __expf(mrow[r] - mn);
      mrow[r] = mn;
      float acc = 0.f;
      #pragma unroll
      for (int t2=0;t2<4;++t2){ p[t2][r] = __expf(p[t2][r] - mn); acc += p[t2][r]; }
      #pragma unroll
      for (int off=1; off<16; off<<=1) acc += __shfl_xor(acc, off);
      lrow[r] = lrow[r]*alpha[r] + acc;
    }
    #pragma unroll
    for (int n=0;n<4;++n)
      #pragma unroll
      for (int r=0;r<4;++r) oacc[n][r] *= alpha[r];

    #pragma unroll
    for (int t2=0;t2<4;++t2)
      #pragma unroll
      for (int r=0;r<4;++r){
        int q = lg*4 + r;
        int cb = (t2*2 + (lo>>3)) ^ (q & 7);
        pw[q*64 + cb*8 + (lo & 7)] = f2b(p[t2][r]);
      }
    asm volatile("" ::: "memory");
    #pragma unroll
    for (int kk=0;kk<2;++kk){
      s16x8 pa = *(const s16x8*)&pw[lo*64 + (((kk*4 + lg) ^ swz)*8)];
      #pragma unroll
      for (int n=0;n<4;++n){
        s16x8 vf = *(const s16x8*)&Vc[(n*16 + lo)*64 + (((kk*4 + lg) ^ swz)*8)];
        oacc[n] = __builtin_amdgcn_mfma_f32_16x16x32_bf16(pa, vf, oacc[n], 0,0,0);
      }
    }
    __syncthreads();
  }

  float inv[4];
  #pragma unroll
  for (int r=0;r<4;++r) inv[r] = 1.f / lrow[r];
  #pragma unroll
  for (int n=0;n<4;++n)
    #pragma unroll
    for (int r=0;r<4;++r){
      int row = q0 + lg*4 + r;
      int col = h*64 + n*16 + lo;
      obf[((size_t)(b*L_ + row))*512 + col] = f2b(oacc[n][r]*inv[r]);
    }
}

// ---------------- LayerNorm (optional residual add, optional gelu) ----------------
__global__ __launch_bounds__(256) void k_ln(const float* __restrict__ X, const float* __restrict__ R,
    const float* __restrict__ gw, const float* __restrict__ bw,
    float* __restrict__ outF, u16* __restrict__ outB, int dogelu)
{
  int l = threadIdx.x & 63, w = threadIdx.x >> 6;
  size_t row = (size_t)blockIdx.x*4 + w;
  const float4* x4 = (const float4*)(X + row*D_);
  float4 a0 = x4[l*2], a1 = x4[l*2+1];
  if (R){
    const float4* r4 = (const float4*)(R + row*D_);
    float4 c0 = r4[l*2], c1 = r4[l*2+1];
    a0.x+=c0.x; a0.y+=c0.y; a0.z+=c0.z; a0.w+=c0.w;
    a1.x+=c1.x; a1.y+=c1.y; a1.z+=c1.z; a1.w+=c1.w;
  }
  float v[8] = {a0.x,a0.y,a0.z,a0.w,a1.x,a1.y,a1.z,a1.w};
  float s = 0.f, q = 0.f;
  #pragma unroll
  for (int j=0;j<8;++j){ s += v[j]; q += v[j]*v[j]; }
  #pragma unroll
  for (int off=1; off<64; off<<=1){ s += __shfl_xor(s, off); q += __shfl_xor(q, off); }
  float mean = s * (1.f/D_);
  float var  = q * (1.f/D_) - mean*mean;
  float rstd = rsqrtf(var + 1e-5f);
  int c0i = l*8;
  #pragma unroll
  for (int j=0;j<8;++j){
    int c = c0i + j;
    float t = (v[j] - mean)*rstd*gw[c] + bw[c];
    if (dogelu) t = gelu_exact(t);
    if (outF) outF[row*D_ + c] = t;
    if (outB) outB[row*D_ + c] = f2b(t);
  }
}

// ---------------- final projection, split-K two-stage ----------------
__global__ __launch_bounds__(256) void k_proj1(const float* __restrict__ g, const float* __restrict__ pw,
    float* __restrict__ pp)
{
  int b = blockIdx.x, nc = blockIdx.y, kc = blockIdx.z, t = threadIdx.x;
  const float4* g4 = (const float4*)(g  + (size_t)b*(L_*D_) + (size_t)kc*32768);
  const float4* w4 = (const float4*)(pw + (size_t)nc*(L_*D_) + (size_t)kc*32768);
  float acc = 0.f;
  for (int k = t; k < 8192; k += 256){
    float4 a = g4[k], c = w4[k];
    acc += a.x*c.x + a.y*c.y + a.z*c.z + a.w*c.w;
  }
  #pragma unroll
  for (int off=1; off<64; off<<=1) acc += __shfl_xor(acc, off);
  __shared__ float red[4];
  if ((t & 63) == 0) red[t>>6] = acc;
  __syncthreads();
  if (t == 0) pp[((b*NC_ + nc)<<3) + kc] = red[0]+red[1]+red[2]+red[3];
}
__global__ void k_proj2(const float* __restrict__ pp, const float* __restrict__ pb,
                        float* __restrict__ out){
  int t = threadIdx.x;
  float s = 0.f;
  #pragma unroll
  for (int k=0;k<8;++k) s += pp[t*8 + k];
  out[t] = s + pb[t & 7];
}

// ---------------- launcher ----------------
extern "C" void kernel_launch(void* const* d_in, const int* in_sizes, int n_in,
                              void* d_out, int out_size, void* d_ws, size_t ws_size,
                              hipStream_t stream)
{
  const float* x_enc        = (const float*)d_in[0];
  const float* emb_conv_w   = (const float*)d_in[1];
  const float* tau_conv_w   = (const float*)d_in[2];
  const float* tau_w1       = (const float*)d_in[3];
  const float* tau_b1       = (const float*)d_in[4];
  const float* tau_w2       = (const float*)d_in[5];
  const float* tau_b2       = (const float*)d_in[6];
  const float* tau_w3       = (const float*)d_in[7];
  const float* delta_conv_w = (const float*)d_in[8];
  const float* delta_w1     = (const float*)d_in[9];
  const float* delta_b1     = (const float*)d_in[10];
  const float* delta_w2     = (const float*)d_in[11];
  const float* delta_b2     = (const float*)d_in[12];
  const float* delta_w3     = (const float*)d_in[13];
  const float* Wq  = (const float*)d_in[14];
  const float* bq  = (const float*)d_in[15];
  const float* Wk  = (const float*)d_in[16];
  const float* bk  = (const float*)d_in[17];
  const float* Wv  = (const float*)d_in[18];
  const float* bv  = (const float*)d_in[19];
  const float* Wo  = (const float*)d_in[20];
  const float* bo  = (const float*)d_in[21];
  const float* ff_w1 = (const float*)d_in[22];
  const float* ff_b1 = (const float*)d_in[23];
  const float* ff_w2 = (const float*)d_in[24];
  const float* ff_b2 = (const float*)d_in[25];
  const float* ln1_g = (const float*)d_in[26];
  const float* ln1_b = (const float*)d_in[27];
  const float* ln2_g = (const float*)d_in[28];
  const float* ln2_b = (const float*)d_in[29];
  const float* norm_g = (const float*)d_in[30];
  const float* norm_b = (const float*)d_in[31];
  const float* proj_w = (const float*)d_in[32];
  const float* proj_b = (const float*)d_in[33];
  (void)in_sizes; (void)n_in; (void)out_size; (void)ws_size;

  char* ws = (char*)d_ws;
  size_t off = 0;
  auto alloc = [&](size_t n){ size_t o = off; off += (n + 255) & ~(size_t)255; return o; };
  float* xf    = (float*)(ws + alloc((size_t)NTOK*512*4));
  u16*   xb    = (u16*)  (ws + alloc((size_t)NTOK*512*2));
  char*  U     =          ws + alloc((size_t)NTOK*2048*2);   // union: qkv | h1 | awin (+obf tail)
  u16*   qkv   = (u16*)U;
  u16*   h1    = (u16*)U;
  u16*   awin  = (u16*)U;
  u16*   obf   = (u16*)(U + (size_t)NTOK*1536*2);
  u16*   vT    = (u16*)  (ws + alloc((size_t)NTOK*512*2));
  float* tmp   = (float*)(ws + alloc((size_t)NTOK*512*4));
  float* pe    = (float*)(ws + alloc((size_t)512*512*4));
  u16*   WqkvB = (u16*)  (ws + alloc((size_t)EL_*1536*512*2));
  u16*   WoB   = (u16*)  (ws + alloc((size_t)EL_*512*512*2));
  u16*   W1B   = (u16*)  (ws + alloc((size_t)EL_*2048*512*2));
  u16*   W2B   = (u16*)  (ws + alloc((size_t)EL_*512*2048*2));
  u16*   embB  = (u16*)  (ws + alloc((size_t)512*192*2));
  float* bqkv  = (float*)(ws + alloc((size_t)EL_*1536*4));
  float* meanb = (float*)(ws + alloc(2048*4));
  float* stdb  = (float*)(ws + alloc(2048*4));
  float* taub  = (float*)(ws + alloc(256));
  float* deltab= (float*)(ws + alloc((size_t)B_*512*4));
  float* pp    = (float*)(ws + alloc((size_t)B_*NC_*8*4));

  k_packqkv<<<(EL_*1536*512+255)/256, 256, 0, stream>>>(Wq, Wk, Wv, WqkvB);
  k_packb  <<<(EL_*1536+255)/256,     256, 0, stream>>>(bq, bk, bv, bqkv);
  k_f2b    <<<(EL_*512*512+255)/256,  256, 0, stream>>>(Wo, WoB, EL_*512*512);
  k_f2b    <<<(EL_*2048*512+255)/256, 256, 0, stream>>>(ff_w1, W1B, EL_*2048*512);
  k_f2b    <<<(EL_*512*2048+255)/256, 256, 0, stream>>>(ff_w2, W2B, EL_*512*2048);
  k_embw   <<<(D_*192+255)/256,       256, 0, stream>>>(emb_conv_w, embB);

  k_stats<<<B_, 256, 0, stream>>>(x_enc, meanb, stdb);
  k_mlp<<<dim3(B_,2), 256, 0, stream>>>(x_enc, meanb, stdb,
      tau_conv_w, tau_w1, tau_b1, tau_w2, tau_b2, tau_w3,
      delta_conv_w, delta_w1, delta_b1, delta_w2, delta_b2, delta_w3,
      taub, deltab);
  k_pe  <<<(L_*D_/2+255)/256, 256, 0, stream>>>(pe);
  k_awin<<<(NTOK*192+255)/256, 256, 0, stream>>>(x_enc, awin);

  k_gemm<<<dim3(4,128), 256, 0, stream>>>(awin, embB, NTOK, 512, 192, nullptr, pe, 0, xf, xb);

  for (int e = 0; e < EL_; ++e){
    k_gemm<<<dim3(12,128), 256, 0, stream>>>(xb, WqkvB + (size_t)e*1536*512, NTOK, 1536, 512,
                                             bqkv + e*1536, nullptr, 0, nullptr, qkv);
    k_vt  <<<dim3(8,8,32), 256, 0, stream>>>(qkv, vT);
    k_attn<<<2048, 256, 0, stream>>>(qkv, vT, taub, deltab, obf);
    k_gemm<<<dim3(4,128), 256, 0, stream>>>(obf, WoB + (size_t)e*512*512, NTOK, 512, 512,
                                            bo + e*512, nullptr, 0, tmp, nullptr);
    k_ln  <<<NTOK/4, 256, 0, stream>>>(xf, tmp, ln1_g + e*512, ln1_b + e*512, xf, xb, 0);
    k_gemm<<<dim3(16,128), 256, 0, stream>>>(xb, W1B + (size_t)e*2048*512, NTOK, 2048, 512,
                                             ff_b1 + e*2048, nullptr, 1, nullptr, h1);
    k_gemm<<<dim3(4,128), 256, 0, stream>>>(h1, W2B + (size_t)e*512*2048, NTOK, 512, 2048,
                                            ff_b2 + e*512, nullptr, 0, tmp, nullptr);
    k_ln  <<<NTOK/4, 256, 0, stream>>>(xf, tmp, ln2_g + e*512, ln2_b + e*512, xf,
                                       (e == EL_-1) ? nullptr : xb, 0);
  }

  k_ln   <<<NTOK/4, 256, 0, stream>>>(xf, nullptr, norm_g, norm_b, tmp, nullptr, 1);
  k_proj1<<<dim3(B_,NC_,8), 256, 0, stream>>>(tmp, proj_w, pp);
  k_proj2<<<1, 256, 0, stream>>>(pp, proj_b, (float*)d_out);
}